// Round 1
// baseline (18521.405 us; speedup 1.0000x reference)
//
#include <hip/hip_runtime.h>
#include <cfloat>

// Problem constants (match reference).
#define B_   16
#define P_   196
#define D_   768
#define N_   2048
#define K_   20
#define PS_  16
#define NR_  14
#define IMG_ 224   // NR_*PS_

// ---------------------------------------------------------------------------
// Kernel 1: sim[b,p,n] = sum_d test[b,p,d] * train[p,d,n], exact fp64 accumulate
// (fp32*fp32 products are exact in fp64 -> ordering identical to previous
//  passing version). grid = (P_, 4); block 256; each thread: 2 consecutive n,
//  all 16 b. 8-d chunks with double-buffered prefetch (64 B/thread in flight)
//  and ds_read_b128 on the LDS A-tile.
// ---------------------------------------------------------------------------
__global__ __launch_bounds__(256, 3) void sim_kernel(
    const float* __restrict__ test,   // [B,P,D]
    const float* __restrict__ train,  // [P,D,N]
    double* __restrict__ sim)         // [B,P,N]
{
    __shared__ float As[B_ * D_];  // 48 KB -> 3 blocks/CU
    const int p   = blockIdx.x;
    const int nc  = blockIdx.y;    // 0..3
    const int tid = threadIdx.x;

    for (int i = tid * 4; i < B_ * D_; i += 256 * 4) {
        const int b = i / D_;
        const int d = i - b * D_;
        *(float4*)(As + i) = *(const float4*)(test + ((size_t)b * P_ + p) * D_ + d);
    }
    __syncthreads();

    const int n0 = nc * 512 + tid * 2;
    const float* tp = train + (size_t)p * D_ * N_ + n0;

    double acc0[B_], acc1[B_];
    #pragma unroll
    for (int b = 0; b < B_; ++b) { acc0[b] = 0.0; acc1[b] = 0.0; }

    float2 tc[8], tn[8];
    #pragma unroll
    for (int j = 0; j < 8; ++j) tc[j] = *(const float2*)(tp + (size_t)j * N_);

    for (int d = 0; d < D_; d += 8) {
        // issue next chunk's 8 loads before touching tc (hide HBM latency)
        if (d + 8 < D_) {
            #pragma unroll
            for (int j = 0; j < 8; ++j)
                tn[j] = *(const float2*)(tp + (size_t)(d + 8 + j) * N_);
        }
        double t0[8], t1[8];
        #pragma unroll
        for (int j = 0; j < 8; ++j) { t0[j] = (double)tc[j].x; t1[j] = (double)tc[j].y; }
        #pragma unroll
        for (int b = 0; b < B_; ++b) {
            float av[8];
            *(float4*)(av)     = *(const float4*)(As + b * D_ + d);      // ds_read_b128
            *(float4*)(av + 4) = *(const float4*)(As + b * D_ + d + 4);  // ds_read_b128
            #pragma unroll
            for (int j = 0; j < 8; ++j) {
                const double ad = (double)av[j];
                acc0[b] += ad * t0[j];
                acc1[b] += ad * t1[j];
            }
        }
        if (d + 8 < D_) {
            #pragma unroll
            for (int j = 0; j < 8; ++j) tc[j] = tn[j];
        }
    }

    #pragma unroll
    for (int b = 0; b < B_; ++b) {
        const size_t o = ((size_t)b * P_ + p) * N_ + n0;
        double2 w; w.x = acc0[b]; w.y = acc1[b];
        *(double2*)(sim + o) = w;
    }
}

// ---------------------------------------------------------------------------
// Kernel 2: top-K per row. One WAVE per (b,p) row, row cached in registers
// (32 doubles/lane), iterative argmax via __shfl_xor butterfly with
// (value, lowest-index) tie-break. No LDS, no __syncthreads.
// ---------------------------------------------------------------------------
__global__ __launch_bounds__(256) void topk_kernel(
    const double* __restrict__ sim,  // [B*P, N]
    float* __restrict__ dist,        // [B*P, K]
    int* __restrict__ idxout)        // [B*P, K]
{
    const int lane = threadIdx.x & 63;
    const int row  = blockIdx.x * 4 + (threadIdx.x >> 6);
    const double* rp = sim + (size_t)row * N_;

    double v[32];
    #pragma unroll
    for (int c = 0; c < 16; ++c) {                 // coalesced 16B/lane
        const double2 t = *(const double2*)(rp + c * 128 + lane * 2);
        v[2 * c]     = t.x;
        v[2 * c + 1] = t.y;
    }

    for (int it = 0; it < K_; ++it) {
        // lane-local argmax (j ascending => n ascending => strict '>' keeps lowest n)
        double bv = v[0];
        int    bn = lane * 2;
        #pragma unroll
        for (int j = 1; j < 32; ++j) {
            const int n = (j >> 1) * 128 + lane * 2 + (j & 1);
            if (v[j] > bv) { bv = v[j]; bn = n; }
        }
        // wave butterfly reduce, tie -> lower index
        #pragma unroll
        for (int off = 32; off; off >>= 1) {
            const double ov = __shfl_xor(bv, off, 64);
            const int    on = __shfl_xor(bn, off, 64);
            if (ov > bv || (ov == bv && on < bn)) { bv = ov; bn = on; }
        }
        if (lane == 0) {
            dist[(size_t)row * K_ + it]   = (float)bv;
            idxout[(size_t)row * K_ + it] = bn;
        }
        // invalidate winner (static indices keep v[] in registers)
        #pragma unroll
        for (int j = 0; j < 32; ++j) {
            const int n = (j >> 1) * 128 + lane * 2 + (j & 1);
            if (n == bn) v[j] = -DBL_MAX;
        }
    }
}

// ---------------------------------------------------------------------------
// Kernel 3: grid[b,k,y,x] = labels[p, s, idx[b,p,k]], p=(y/16)*14+(x/16),
// s=(y%16)*16+(x%16). Block = one (p, y%16): needs exactly the 16 contiguous
// rows labels[p, sy*16 .. +16, :] (128 KB, read fully coalesced once) staged
// as u8 in LDS (labels < 21). Gathers become LDS reads; stride 2064 breaks
// the 16-way bank conflict of the read phase. Writes: 64 B segments.
// ---------------------------------------------------------------------------
#define LSTRIDE 2064  // 2048 + 16 pad
__global__ __launch_bounds__(256) void grid_kernel(
    const int* __restrict__ labels,  // [P, 256, N]
    const int* __restrict__ idxin,   // [B, P, K]
    float* __restrict__ out)         // [B, K, 224, 224]
{
    __shared__ unsigned char lab[16 * LSTRIDE];  // 33 KB
    const int p   = blockIdx.x;   // 0..195
    const int sy  = blockIdx.y;   // 0..15 (y within patch)
    const int tid = threadIdx.x;

    // Stage 16 rows x 2048 labels -> u8 LDS. Source is one contiguous 128 KB slab.
    const int* src = labels + (size_t)(p * 256 + sy * 16) * N_;
    for (int i = tid; i < 8192; i += 256) {        // int4 granularity
        const int4 v = ((const int4*)src)[i];
        const int g = i * 4;                       // element offset
        const int r = g >> 11;                     // row 0..15
        const int n = g & 2047;
        const unsigned pk = (unsigned)v.x | ((unsigned)v.y << 8) |
                            ((unsigned)v.z << 16) | ((unsigned)v.w << 24);
        *(unsigned*)(lab + r * LSTRIDE + n) = pk;
    }
    __syncthreads();

    const int y     = (p / NR_) * PS_ + sy;
    const int xbase = (p % NR_) * PS_;

    // 320 (b,k) pairs x 16 x-pixels = 5120 outputs; 20 per thread.
    #pragma unroll
    for (int it = 0; it < 20; ++it) {
        const int px = tid + it * 256;
        const int xx = px & 15;
        const int bk = px >> 4;        // 0..319
        const int b  = bk / K_;
        const int k  = bk - b * K_;
        const int n  = idxin[((size_t)b * P_ + p) * K_ + k];
        const float val = (float)lab[xx * LSTRIDE + n];
        out[(((size_t)b * K_ + k) * IMG_ + y) * IMG_ + xbase + xx] = val;
    }
}

// ---------------------------------------------------------------------------
extern "C" void kernel_launch(void* const* d_in, const int* in_sizes, int n_in,
                              void* d_out, int out_size, void* d_ws, size_t ws_size,
                              hipStream_t stream) {
    const float* test   = (const float*)d_in[0];  // [B,P,D] fp32
    const float* train  = (const float*)d_in[1];  // [P,D,N] fp32
    const int*   labels = (const int*)d_in[2];    // [P,256,N] int32

    float* out  = (float*)d_out;
    float* dist = out;                        // [B,P,K]
    float* grid = out + (size_t)B_ * P_ * K_; // [B,K,224,224]

    double* sim  = (double*)d_ws;                                   // 51.4 MB
    int*    idxw = (int*)((char*)d_ws + (size_t)B_ * P_ * N_ * sizeof(double));

    sim_kernel<<<dim3(P_, N_ / 512), 256, 0, stream>>>(test, train, sim);
    topk_kernel<<<dim3(B_ * P_ / 4), 256, 0, stream>>>(sim, dist, idxw);
    grid_kernel<<<dim3(P_, PS_), 256, 0, stream>>>(labels, idxw, grid);
}